// Round 5
// baseline (231.866 us; speedup 1.0000x reference)
//
#include <hip/hip_runtime.h>

// RoPE: out[..., 2k]   = cos*x[...,2k] - sin*x[...,2k+1]
//       out[..., 2k+1] = sin*x[...,2k] + cos*x[...,2k+1]
// x: (4,16,4096,128) fp32, tables: (8192,64) fp32, token_positions: (4096,) i32.
// Min HBM traffic 268 MB -> ~42.6 us at the 6.3 TB/s copy ceiling.
//
// Round-4 lesson: removing the gather chain was NEUTRAL -> not latency-bound
// on the gather. Rounds 0/4 share the real cost: 1 float4/thread, 131072
// short-lived waves (2-3 VMEM each). This round: grid-stride (Guideline 11).
//   grid = 2048 blocks x 256 thr; stride = 524288 float4 = 4 (b,h)-slabs.
//   (tid + k*stride) & 131071 == tid & 131071  -> each thread's (s,d) position
//   is INVARIANT across iterations: gather tok_pos + cos/sin ONCE per thread,
//   reuse for all 16 float4s. VMEM/float4: 3.0 -> ~2.2; 4 independent x-loads
//   in flight per thread; wave setup amortized 16x.

typedef float f4 __attribute__((ext_vector_type(4)));
typedef float f2 __attribute__((ext_vector_type(2)));

constexpr int SEQ        = 4096;
constexpr int D_K        = 128;
constexpr int F4_PER_ROW = D_K / 4;    // 32 float4 per 128-float row
constexpr int BLOCK      = 256;
constexpr int GRID       = 2048;       // 256 CU x 8 blocks/CU

__global__ __launch_bounds__(BLOCK) void rope_kernel(
    const f4* __restrict__ x,
    const int* __restrict__ tok_pos,
    const f2* __restrict__ cos_t,      // (8192, 32) as float2
    const f2* __restrict__ sin_t,
    f4*       __restrict__ out,
    const int n4)                      // total float4 count
{
    const int tid    = blockIdx.x * BLOCK + threadIdx.x;   // 0..524287
    const int stride = GRID * BLOCK;                       // 524288 float4

    // (s, d)-position is invariant across the grid-stride loop: stride is a
    // multiple of the 131072-float4 (b,h) slab size. Gather once, reuse 16x.
    const int within = tid & (F4_PER_ROW - 1);
    const int s      = (tid >> 5) & (SEQ - 1);
    const int p      = tok_pos[s];
    const f2 c  = cos_t[p * F4_PER_ROW + within];
    const f2 sn = sin_t[p * F4_PER_ROW + within];

    // 8,388,608 / 524,288 = 16 iterations, unrolled 4x: 4 independent
    // lane-contiguous (16B/lane) loads in flight per thread.
    for (int k = tid; k < n4; k += 4 * stride) {
        f4 a0 = __builtin_nontemporal_load(&x[k]);
        f4 a1 = __builtin_nontemporal_load(&x[k + stride]);
        f4 a2 = __builtin_nontemporal_load(&x[k + 2 * stride]);
        f4 a3 = __builtin_nontemporal_load(&x[k + 3 * stride]);

        f4 o0, o1, o2, o3;
        o0.x = c.x * a0.x - sn.x * a0.y;  o0.y = sn.x * a0.x + c.x * a0.y;
        o0.z = c.y * a0.z - sn.y * a0.w;  o0.w = sn.y * a0.z + c.y * a0.w;
        o1.x = c.x * a1.x - sn.x * a1.y;  o1.y = sn.x * a1.x + c.x * a1.y;
        o1.z = c.y * a1.z - sn.y * a1.w;  o1.w = sn.y * a1.z + c.y * a1.w;
        o2.x = c.x * a2.x - sn.x * a2.y;  o2.y = sn.x * a2.x + c.x * a2.y;
        o2.z = c.y * a2.z - sn.y * a2.w;  o2.w = sn.y * a2.z + c.y * a2.w;
        o3.x = c.x * a3.x - sn.x * a3.y;  o3.y = sn.x * a3.x + c.x * a3.y;
        o3.z = c.y * a3.z - sn.y * a3.w;  o3.w = sn.y * a3.z + c.y * a3.w;

        __builtin_nontemporal_store(o0, &out[k]);
        __builtin_nontemporal_store(o1, &out[k + stride]);
        __builtin_nontemporal_store(o2, &out[k + 2 * stride]);
        __builtin_nontemporal_store(o3, &out[k + 3 * stride]);
    }
}

extern "C" void kernel_launch(void* const* d_in, const int* in_sizes, int n_in,
                              void* d_out, int out_size, void* d_ws, size_t ws_size,
                              hipStream_t stream) {
    const f4*  x       = (const f4*)d_in[0];
    const int* tok_pos = (const int*)d_in[1];
    const f2*  cos_t   = (const f2*)d_in[2];
    const f2*  sin_t   = (const f2*)d_in[3];
    f4*        out     = (f4*)d_out;

    const int n4 = out_size / 4;   // out_size in ELEMENTS -> 8,388,608 float4
    // n4 / (GRID*BLOCK) = 16 exactly; the unroll-4 loop needs n4 % (4*stride)==0,
    // which holds (8,388,608 = 16 x 524,288).
    rope_kernel<<<GRID, BLOCK, 0, stream>>>(x, tok_pos, cos_t, sin_t, out, n4);
}

// Round 6
// 231.643 us; speedup vs baseline: 1.0010x; 1.0010x over previous
//
#include <hip/hip_runtime.h>

// RoPE: out[..., 2k]   = cos*x[...,2k] - sin*x[...,2k+1]
//       out[..., 2k+1] = sin*x[...,2k] + cos*x[...,2k+1]
// x: (4,16,4096,128) fp32, tables: (8192,64) fp32, token_positions: (4096,) i32.
// Min HBM traffic 268 MB -> ~42.6 us at the 6.3 TB/s copy ceiling.
//
// Experiment ledger:
//   R0: 1 f4/thread, direct gather, cached        -> 227.8 (best)
//   R3: 32B/thread chunks (broke lane contiguity) -> 241.0
//   R4: fused table, nt                           -> 228.5
//   R5: grid-stride x16 + table reuse, nt         -> 231.9
// Gather chain, table VMEM count, wave churn all ruled out as limiters.
// This round isolates nt: R4 structure (fused table, 3 VMEM/f4, no dependent
// gather) with fully CACHED loads/stores. Prep stores plain so the 2 MiB fused
// table lands L2-hot for the main kernel.

typedef float f4 __attribute__((ext_vector_type(4)));
typedef float f2 __attribute__((ext_vector_type(2)));

constexpr int SEQ        = 4096;
constexpr int D_K        = 128;
constexpr int F4_PER_ROW = D_K / 4;          // 32 float4 per 128-float row
constexpr int FUSED_F4   = SEQ * F4_PER_ROW; // 131072 float4 = 2 MiB
constexpr int BLOCK      = 256;

__global__ __launch_bounds__(BLOCK) void rope_prep(
    const int* __restrict__ tok_pos,
    const f2*  __restrict__ cos_t,   // (8192, 32) as float2
    const f2*  __restrict__ sin_t,
    f4*        __restrict__ fused)   // (4096, 32) float4: (c0,s0,c1,s1)
{
    const int i = blockIdx.x * BLOCK + threadIdx.x;   // 0..131071
    const int j = i & (F4_PER_ROW - 1);
    const int s = i >> 5;
    const int p = tok_pos[s];                         // gather happens ONCE here
    const f2 c  = cos_t[p * F4_PER_ROW + j];
    const f2 sn = sin_t[p * F4_PER_ROW + j];
    f4 t;
    t.x = c.x;  t.y = sn.x;  t.z = c.y;  t.w = sn.y;
    fused[i] = t;                                     // plain store: stay L2-hot
}

__global__ __launch_bounds__(BLOCK) void rope_main(
    const f4* __restrict__ x,
    const f4* __restrict__ fused,
    f4*       __restrict__ out)
{
    const int i = blockIdx.x * BLOCK + threadIdx.x;   // 16B/lane, wave-contiguous
    const f4 t = fused[i & (FUSED_F4 - 1)];           // L2-resident, no indirection
    const f4 v = x[i];                                // cached path (nt removed)
    f4 o;
    o.x = t.x * v.x - t.y * v.y;
    o.y = t.y * v.x + t.x * v.y;
    o.z = t.z * v.z - t.w * v.w;
    o.w = t.w * v.z + t.z * v.w;
    out[i] = o;                                       // cached path (nt removed)
}

// Fallback if workspace < 2 MiB: proven round-0 kernel.
__global__ __launch_bounds__(BLOCK) void rope_fallback(
    const f4* __restrict__ x,
    const int* __restrict__ tok_pos,
    const f2* __restrict__ cos_t,
    const f2* __restrict__ sin_t,
    f4*       __restrict__ out)
{
    const int i = blockIdx.x * BLOCK + threadIdx.x;
    const int within = i & (F4_PER_ROW - 1);
    const int row    = i >> 5;
    const int s      = row & (SEQ - 1);
    const int p      = tok_pos[s];
    const f2 c  = cos_t[p * F4_PER_ROW + within];
    const f2 sn = sin_t[p * F4_PER_ROW + within];
    const f4 v = x[i];
    f4 o;
    o.x = c.x * v.x - sn.x * v.y;
    o.y = sn.x * v.x + c.x * v.y;
    o.z = c.y * v.z - sn.y * v.w;
    o.w = sn.y * v.z + c.y * v.w;
    out[i] = o;
}

extern "C" void kernel_launch(void* const* d_in, const int* in_sizes, int n_in,
                              void* d_out, int out_size, void* d_ws, size_t ws_size,
                              hipStream_t stream) {
    const f4*  x       = (const f4*)d_in[0];
    const int* tok_pos = (const int*)d_in[1];
    const f2*  cos_t   = (const f2*)d_in[2];
    const f2*  sin_t   = (const f2*)d_in[3];
    f4*        out     = (f4*)d_out;

    const int n4 = out_size / 4;      // out_size in ELEMENTS -> 8,388,608 float4
    const int grid = n4 / BLOCK;      // 32768, exact

    if (ws_size >= (size_t)FUSED_F4 * 16) {
        f4* fused = (f4*)d_ws;
        rope_prep<<<FUSED_F4 / BLOCK, BLOCK, 0, stream>>>(tok_pos, cos_t, sin_t, fused);
        rope_main<<<grid, BLOCK, 0, stream>>>(x, fused, out);
    } else {
        rope_fallback<<<grid, BLOCK, 0, stream>>>(x, tok_pos, cos_t, sin_t, out);
    }
}

// Round 7
// 230.731 us; speedup vs baseline: 1.0049x; 1.0040x over previous
//
#include <hip/hip_runtime.h>

// RoPE: out[..., 2k]   = cos*x[...,2k] - sin*x[...,2k+1]
//       out[..., 2k+1] = sin*x[...,2k] + cos*x[...,2k+1]
// x: (4,16,4096,128) fp32, tables: (8192,64) fp32, token_positions: (4096,) i32.
// Min HBM traffic 268 MB -> ~42.6 us at the 6.3 TB/s copy ceiling.
//
// Experiment ledger (end-to-end; ~160 us is fixed harness fills):
//   R0: 1 f4/thread, direct gather, cached        -> 227.8 (best)
//   R3: 32B/thread chunks (broke lane contiguity) -> 241.0
//   R4: fused table (3 VMEM/f4), nt               -> 228.5
//   R5: grid-stride x16, 8MiB-apart streams, nt   -> 231.9
//   R6: fused table, cached                       -> 231.6
// Ruled out: gather chain, table VMEM count, nt hints, scattered coarsening.
// This round: the untried cell — LOCAL coarsening with intact per-instruction
// contiguity. Thread's u-th access = base + u*BLOCK: each wave issues 4
// back-to-back 1KiB-coalesced loads over consecutive memory (copy-kernel
// shape), 4 independent chains/thread, block covers 16 KiB contiguous.

typedef float f4 __attribute__((ext_vector_type(4)));
typedef float f2 __attribute__((ext_vector_type(2)));

constexpr int SEQ        = 4096;
constexpr int D_K        = 128;
constexpr int F4_PER_ROW = D_K / 4;    // 32 float4 per 128-float row
constexpr int BLOCK      = 256;
constexpr int UNROLL     = 4;

__global__ __launch_bounds__(BLOCK) void rope_kernel(
    const f4* __restrict__ x,
    const int* __restrict__ tok_pos,
    const f2* __restrict__ cos_t,      // (8192, 32) as float2
    const f2* __restrict__ sin_t,
    f4*       __restrict__ out)
{
    const int base = blockIdx.x * (BLOCK * UNROLL) + threadIdx.x;

    // Issue all 4 x-loads up front: 4 independent, back-to-back, each one a
    // perfectly coalesced 1 KiB wave transaction on consecutive addresses.
    f4 a[UNROLL];
#pragma unroll
    for (int u = 0; u < UNROLL; ++u)
        a[u] = x[base + u * BLOCK];

    // Table gathers (L1/L2-hit): within-row index is invariant across u
    // (BLOCK=256 is a multiple of 32); s advances by 8 rows per u.
    const int within = base & (F4_PER_ROW - 1);
    f2 c[UNROLL], sn[UNROLL];
#pragma unroll
    for (int u = 0; u < UNROLL; ++u) {
        const int s = ((base + u * BLOCK) >> 5) & (SEQ - 1);
        const int p = tok_pos[s];
        c[u]  = cos_t[p * F4_PER_ROW + within];
        sn[u] = sin_t[p * F4_PER_ROW + within];
    }

#pragma unroll
    for (int u = 0; u < UNROLL; ++u) {
        f4 o;
        o.x = c[u].x * a[u].x - sn[u].x * a[u].y;
        o.y = sn[u].x * a[u].x + c[u].x * a[u].y;
        o.z = c[u].y * a[u].z - sn[u].y * a[u].w;
        o.w = sn[u].y * a[u].z + c[u].y * a[u].w;
        out[base + u * BLOCK] = o;
    }
}

extern "C" void kernel_launch(void* const* d_in, const int* in_sizes, int n_in,
                              void* d_out, int out_size, void* d_ws, size_t ws_size,
                              hipStream_t stream) {
    const f4*  x       = (const f4*)d_in[0];
    const int* tok_pos = (const int*)d_in[1];
    const f2*  cos_t   = (const f2*)d_in[2];
    const f2*  sin_t   = (const f2*)d_in[3];
    f4*        out     = (f4*)d_out;

    const int n4   = out_size / 4;              // out_size in ELEMENTS -> 8,388,608
    const int grid = n4 / (BLOCK * UNROLL);     // 8192, exact

    rope_kernel<<<grid, BLOCK, 0, stream>>>(x, tok_pos, cos_t, sin_t, out);
}

// Round 8
// 227.061 us; speedup vs baseline: 1.0212x; 1.0162x over previous
//
#include <hip/hip_runtime.h>

// RoPE: out[..., 2k]   = cos*x[...,2k] - sin*x[...,2k+1]
//       out[..., 2k+1] = sin*x[...,2k] + cos*x[...,2k+1]
// x: (4,16,4096,128) fp32, tables: (8192,64) fp32, token_positions: (4096,) i32.
// Memory-bound: 128 MiB in + 128 MiB out; tables ~2 MiB live set (L2-resident).
//
// FINAL FORM — experiment ledger (end-to-end; ~161 us is fixed harness fills,
// kernel portion in parens):
//   R0: 1 f4/thread, direct gather, cached        -> 227.8 (~66.8 us)  BEST
//   R3: 32B/thread chunks (broke lane contiguity) -> 241.0 (~80 us)
//   R4: fused interleaved table (3 VMEM/f4), nt   -> 228.5 (~67.5 us)
//   R5: grid-stride x16 + per-thread table reuse  -> 231.9 (~71 us)
//   R6: fused table, cached                       -> 231.6 (~71 us)
//   R7: local x4 coarsening, contiguous           -> 230.7 (~70 us)
// Jointly falsified as limiters: VMEM instruction count (5 vs 3 per float4:
// no change), gather dependency latency, wave churn, nt cache hints,
// coarsening in any arrangement. The minimal one-f4-per-thread form is the
// floor: ~268 MB moved in ~67 us = ~4.1 TB/s effective for this mixed
// read+write+table-probe pattern. Every added mechanism cost 1-4 us.

constexpr int SEQ      = 4096;
constexpr int D_K      = 128;
constexpr int F4_PER_ROW = D_K / 4;   // 32 float4 per row

__global__ __launch_bounds__(256) void rope_kernel(
    const float4* __restrict__ x,
    const int*    __restrict__ tok_pos,
    const float2* __restrict__ cos_t,   // (8192, 32) as float2
    const float2* __restrict__ sin_t,
    float4*       __restrict__ out)
{
    const int i = blockIdx.x * blockDim.x + threadIdx.x;  // float4 index

    const int within = i & (F4_PER_ROW - 1);   // which float4 in the 128-float row
    const int row    = i >> 5;                 // (b*H + h)*SEQ + s
    const int s      = row & (SEQ - 1);        // SEQ = 4096 (pow2)
    const int p      = tok_pos[s];             // honor the gather

    // Each float4 covers pairs k = 2*within and 2*within+1 -> float2 of tables.
    const float2 c  = cos_t[p * (D_K / 4) + within];
    const float2 sn = sin_t[p * (D_K / 4) + within];

    const float4 v = x[i];
    float4 o;
    o.x = c.x * v.x - sn.x * v.y;
    o.y = sn.x * v.x + c.x * v.y;
    o.z = c.y * v.z - sn.y * v.w;
    o.w = sn.y * v.z + c.y * v.w;
    out[i] = o;
}

extern "C" void kernel_launch(void* const* d_in, const int* in_sizes, int n_in,
                              void* d_out, int out_size, void* d_ws, size_t ws_size,
                              hipStream_t stream) {
    const float4* x       = (const float4*)d_in[0];
    const int*    tok_pos = (const int*)d_in[1];
    const float2* cos_t   = (const float2*)d_in[2];
    const float2* sin_t   = (const float2*)d_in[3];
    float4*       out     = (float4*)d_out;

    const int n4 = out_size / 4;              // out_size in ELEMENTS -> 8,388,608 float4
    const int block = 256;
    const int grid  = n4 / block;             // exact: n4 % 256 == 0

    rope_kernel<<<grid, block, 0, stream>>>(x, tok_pos, cos_t, sin_t, out);
}